// Round 4
// baseline (176.717 us; speedup 1.0000x reference)
//
#include <hip/hip_runtime.h>
#include <hip/hip_fp16.h>

#define IN_F   100000
#define OUT_F  100000
#define NNZ_N  1600000
#define NSLICE 4              // 4 batch slices x 16 batches: 3.2MB/slice < 4MB L2/XCD
#define TC     256

// ---------------------------------------------------------------------------
// Kernel A: x (64, IN) f32 -> xh sliced fp16: xh[s][col][16 batches].
// uint = half2 = batch pair. Element xh_u32[(s*IN_F + col)*8 + u] holds
// batches (16s+2u, 16s+2u+1) of column col. Reads 256B-coalesced; writes
// 256B-contiguous per wave.
// ---------------------------------------------------------------------------
__global__ __launch_bounds__(256) void k_transpose_sliced(
    const float* __restrict__ x, unsigned* __restrict__ xh) {
    __shared__ unsigned tile[TC][33];      // [col][pair], stride 33: write-phase conflict-free
    const int i0 = blockIdx.x * TC;
    const int t  = threadIdx.x;
    const int colr = i0 + t;

    if (colr < IN_F) {
        #pragma unroll 8
        for (int p = 0; p < 32; ++p) {     // pair p -> batches 2p, 2p+1
            const float a = x[(size_t)(2 * p)     * IN_F + colr];
            const float b = x[(size_t)(2 * p + 1) * IN_F + colr];
            const __half2 h = __floats2half2_rn(a, b);
            tile[t][p] = *reinterpret_cast<const unsigned*>(&h);
        }
    }
    __syncthreads();

    const int u  = t & 7;                  // pair within slice [0,8)
    const int c0 = t >> 3;                 // col part [0,32)
    for (int s = 0; s < NSLICE; ++s) {
        for (int cc = c0; cc < TC; cc += 32) {
            const int col = i0 + cc;
            if (col < IN_F)
                xh[((size_t)s * IN_F + col) * 8 + u] = tile[cc][s * 8 + u];
        }
    }
}

// ---------------------------------------------------------------------------
// Kernel B: rstart[r] = lower_bound(rows, r) via linear scan of sorted rows.
// Coalesced 6.4MB read instead of 100K x 21 dependent random loads.
// ---------------------------------------------------------------------------
__global__ __launch_bounds__(256) void k_rowstart_scan(
    const int* __restrict__ rows, int* __restrict__ rstart) {
    const int e = blockIdx.x * 256 + threadIdx.x;
    if (e >= NNZ_N) return;
    const int cur  = rows[e];
    const int prev = (e == 0) ? -1 : rows[e - 1];
    for (int r = prev + 1; r <= cur; ++r) rstart[r] = e;
    if (e == NNZ_N - 1)
        for (int r = cur + 1; r <= OUT_F; ++r) rstart[r] = NNZ_N;
}

__device__ __forceinline__ float2 h2f(unsigned u) {
    const __half2 h = *reinterpret_cast<const __half2*>(&u);
    return __half22float2(h);
}

// ---------------------------------------------------------------------------
// Kernel C: one batch-slice SpMM pass. Block = 512 threads = 8 waves = 64
// rows; each 8-lane group owns ONE row. Lane sub covers batches 2sub,2sub+1
// of the slice (one 4B half2 per edge). 4 edges unrolled -> 4 independent
// gathers in flight. Working set = 3.2MB -> L2-resident.
// ---------------------------------------------------------------------------
__global__ __launch_bounds__(512, 8) void k_spmm_pass(
    const unsigned* __restrict__ xs,      // slice base (uints): col*8 + sub
    const float*    __restrict__ vals,
    const int*      __restrict__ cols,
    const int*      __restrict__ rstart_g,
    const float*    __restrict__ bias,
    float* __restrict__ out, int b0) {
    __shared__ int   rs[65];
    __shared__ float tile[64][17];
    const int r0   = blockIdx.x * 64;
    const int t    = threadIdx.x;
    const int lane = t & 63;
    const int w    = t >> 6;

    if (t < 65) {
        int idx = r0 + t; if (idx > OUT_F) idx = OUT_F;
        rs[t] = rstart_g[idx];
    }
    __syncthreads();

    const int g   = lane >> 3;            // group [0,8) -> row
    const int sub = lane & 7;             // batch pair [0,8)
    const int lj  = (w << 3) + g;         // local row [0,64)
    const int s   = rs[lj];
    const int e   = rs[lj + 1];
    const unsigned* xb = xs + sub;

    float2 acc = {0.f, 0.f};
    for (int base = s; base < e; base += 4) {
        const int e1 = e - 1;
        const int i1 = (base + 1 < e) ? base + 1 : e1;
        const int i2 = (base + 2 < e) ? base + 2 : e1;
        const int i3 = (base + 3 < e) ? base + 3 : e1;
        const int c0 = cols[base], c1 = cols[i1], c2 = cols[i2], c3 = cols[i3];
        const float v0 = vals[base];
        float v1 = vals[i1]; if (base + 1 >= e) v1 = 0.f;
        float v2 = vals[i2]; if (base + 2 >= e) v2 = 0.f;
        float v3 = vals[i3]; if (base + 3 >= e) v3 = 0.f;
        const unsigned u0 = xb[(size_t)c0 << 3];
        const unsigned u1 = xb[(size_t)c1 << 3];
        const unsigned u2 = xb[(size_t)c2 << 3];
        const unsigned u3 = xb[(size_t)c3 << 3];
        float2 f;
        f = h2f(u0); acc.x = fmaf(v0, f.x, acc.x); acc.y = fmaf(v0, f.y, acc.y);
        f = h2f(u1); acc.x = fmaf(v1, f.x, acc.x); acc.y = fmaf(v1, f.y, acc.y);
        f = h2f(u2); acc.x = fmaf(v2, f.x, acc.x); acc.y = fmaf(v2, f.y, acc.y);
        f = h2f(u3); acc.x = fmaf(v3, f.x, acc.x); acc.y = fmaf(v3, f.y, acc.y);
    }
    tile[lj][2 * sub]     = acc.x;
    tile[lj][2 * sub + 1] = acc.y;
    __syncthreads();

    const int rc = r0 + lane;
    if (rc < OUT_F) {
        const float bv = bias[rc];
        for (int bb = w; bb < 16; bb += 8)
            out[(size_t)(b0 + bb) * OUT_F + rc] = tile[lane][bb] + bv;
    }
}

// ---------------------------------------------------------------------------
// Fallback (insufficient ws): gather from native x layout. Correct, slow.
// ---------------------------------------------------------------------------
__global__ __launch_bounds__(256) void k_spmm_fallback(
    const float* __restrict__ x,
    const float* __restrict__ vals,
    const int*   __restrict__ rows,
    const int*   __restrict__ cols,
    const float* __restrict__ bias,
    float* __restrict__ out) {
    __shared__ int   rstart[65];
    __shared__ float tile[64][65];
    const int r0   = blockIdx.x * 64;
    const int t    = threadIdx.x;
    const int lane = t & 63;
    const int w    = t >> 6;
    if (t < 65) {
        const int target = r0 + t;
        int lo = 0, hi = NNZ_N;
        while (lo < hi) {
            const int mid = (lo + hi) >> 1;
            if (rows[mid] < target) lo = mid + 1; else hi = mid;
        }
        rstart[t] = lo;
    }
    __syncthreads();
    for (int j = w; j < 64; j += 4) {
        const int s = rstart[j], e = rstart[j + 1];
        float acc = 0.f;
        const size_t base = (size_t)lane * IN_F;
        for (int idx = s; idx < e; ++idx)
            acc = fmaf(vals[idx], x[base + cols[idx]], acc);
        tile[j][lane] = acc;
    }
    __syncthreads();
    const int c = lane;
    if (r0 + c < OUT_F) {
        const float bv = bias[r0 + c];
        for (int bb = w; bb < 64; bb += 4)
            out[(size_t)bb * OUT_F + (r0 + c)] = tile[c][bb] + bv;
    }
}

extern "C" void kernel_launch(void* const* d_in, const int* in_sizes, int n_in,
                              void* d_out, int out_size, void* d_ws, size_t ws_size,
                              hipStream_t stream) {
    const float* x      = (const float*)d_in[0];
    const float* values = (const float*)d_in[1];
    const float* bias   = (const float*)d_in[2];
    const int*   rows   = (const int*)d_in[3];
    const int*   cols   = (const int*)d_in[4];
    float*       out    = (float*)d_out;

    const size_t xh_bytes = (size_t)NSLICE * IN_F * 8 * sizeof(unsigned); // 12.8 MB
    const size_t rs_off   = (xh_bytes + 255) & ~(size_t)255;
    const size_t need     = rs_off + (size_t)(OUT_F + 1) * sizeof(int);

    const int row_blocks = (OUT_F + 63) / 64;            // 1563
    const int tc_blocks  = (IN_F + TC - 1) / TC;         // 391
    const int sc_blocks  = (NNZ_N + 255) / 256;          // 6250

    if (ws_size >= need) {
        unsigned* xh     = (unsigned*)d_ws;
        int*      rstart = (int*)((char*)d_ws + rs_off);
        k_transpose_sliced<<<tc_blocks, 256, 0, stream>>>(x, xh);
        k_rowstart_scan<<<sc_blocks, 256, 0, stream>>>(rows, rstart);
        for (int s = 0; s < NSLICE; ++s) {
            const unsigned* xs = xh + (size_t)s * IN_F * 8;
            k_spmm_pass<<<row_blocks, 512, 0, stream>>>(
                xs, values, cols, rstart, bias, out, s * 16);
        }
    } else {
        k_spmm_fallback<<<row_blocks, 256, 0, stream>>>(x, values, rows, cols, bias, out);
    }
}

// Round 5
// 131.404 us; speedup vs baseline: 1.3448x; 1.3448x over previous
//
#include <hip/hip_runtime.h>
#include <hip/hip_fp16.h>

#define IN_F   100000
#define OUT_F  100000
#define NNZ_N  1600000
#define TC     256
#define TBLK   ((IN_F + TC - 1) / TC)      // 391 transpose blocks
#define SBLK   ((NNZ_N + 255) / 256)       // 6250 scan/pack blocks

__device__ __forceinline__ float2 h2f(unsigned u) {
    const __half2 h = *reinterpret_cast<const __half2*>(&u);
    return __half22float2(h);
}

// ---------------------------------------------------------------------------
// Prep (fused): blocks [0,TBLK) transpose x (64,IN) f32 -> xh (IN,64) f16
// (u32 index: col*32 + pair, pair p = batches 2p,2p+1). Blocks [TBLK, TBLK+SBLK)
// do the rowstart linear scan over sorted rows AND pack (col,val) -> uint2.
// ---------------------------------------------------------------------------
__global__ __launch_bounds__(256) void k_prep(
    const float* __restrict__ x,
    const int*   __restrict__ rows,
    const int*   __restrict__ cols,
    const float* __restrict__ vals,
    unsigned* __restrict__ xh,
    int*      __restrict__ rstart,
    uint2*    __restrict__ pairs) {
    __shared__ unsigned tile[TC][33];
    const int bid = blockIdx.x;
    const int t   = threadIdx.x;

    if (bid < TBLK) {
        const int i0   = bid * TC;
        const int colr = i0 + t;
        if (colr < IN_F) {
            #pragma unroll 8
            for (int p = 0; p < 32; ++p) {
                const float a = x[(size_t)(2 * p)     * IN_F + colr];
                const float b = x[(size_t)(2 * p + 1) * IN_F + colr];
                const __half2 h = __floats2half2_rn(a, b);
                tile[t][p] = *reinterpret_cast<const unsigned*>(&h);
            }
        }
        __syncthreads();
        const int u  = t & 31;              // batch pair
        const int c8 = t >> 5;
        for (int cc = c8; cc < TC; cc += 8) {
            const int col = i0 + cc;
            if (col < IN_F)
                xh[(size_t)col * 32 + u] = tile[cc][u];
        }
    } else {
        const int e = (bid - TBLK) * 256 + t;
        if (e >= NNZ_N) return;
        const int cur  = rows[e];
        const int prev = (e == 0) ? -1 : rows[e - 1];
        for (int r = prev + 1; r <= cur; ++r) rstart[r] = e;
        if (e == NNZ_N - 1)
            for (int r = cur + 1; r <= OUT_F; ++r) rstart[r] = NNZ_N;
        pairs[e] = make_uint2((unsigned)cols[e], __float_as_uint(vals[e]));
    }
}

// ---------------------------------------------------------------------------
// SpMM: block = 512 threads = 8 waves = 64 rows. Each 8-lane group owns ONE
// row; lane sub in [0,8) loads uint4 = 8 halves = batches 8sub..8sub+7.
// One wave-instruction = 8 distinct edges = 8 cache lines; unroll-4 -> 32
// lines in flight per wave. fp32 accumulate (8 per lane).
// ---------------------------------------------------------------------------
__global__ __launch_bounds__(512, 4) void k_spmm(
    const uint4* __restrict__ xh4,        // col*8 + sub
    const uint2* __restrict__ pairs,
    const int*   __restrict__ rstart_g,
    const float* __restrict__ bias,
    float* __restrict__ out) {
    __shared__ int   rs[65];
    __shared__ float tile[64][65];
    const int r0   = blockIdx.x * 64;
    const int t    = threadIdx.x;
    const int lane = t & 63;
    const int w    = t >> 6;

    if (t < 65) {
        int idx = r0 + t; if (idx > OUT_F) idx = OUT_F;
        rs[t] = rstart_g[idx];
    }
    __syncthreads();

    const int g   = lane >> 3;            // group -> local row
    const int sub = lane & 7;             // batch octet
    const int lj  = (w << 3) + g;
    const int s   = rs[lj];
    const int e   = rs[lj + 1];

    float acc[8];
    #pragma unroll
    for (int i = 0; i < 8; ++i) acc[i] = 0.f;

    for (int base = s; base < e; base += 4) {
        const int e1 = e - 1;
        const int i1 = (base + 1 < e) ? base + 1 : e1;
        const int i2 = (base + 2 < e) ? base + 2 : e1;
        const int i3 = (base + 3 < e) ? base + 3 : e1;
        const uint2 p0 = pairs[base];
        const uint2 p1 = pairs[i1];
        const uint2 p2 = pairs[i2];
        const uint2 p3 = pairs[i3];
        const float v0 = __uint_as_float(p0.y);
        const float v1 = (base + 1 < e) ? __uint_as_float(p1.y) : 0.f;
        const float v2 = (base + 2 < e) ? __uint_as_float(p2.y) : 0.f;
        const float v3 = (base + 3 < e) ? __uint_as_float(p3.y) : 0.f;
        const uint4 u0 = xh4[(size_t)p0.x * 8 + sub];
        const uint4 u1 = xh4[(size_t)p1.x * 8 + sub];
        const uint4 u2 = xh4[(size_t)p2.x * 8 + sub];
        const uint4 u3 = xh4[(size_t)p3.x * 8 + sub];
        float2 f;
        f = h2f(u0.x); acc[0] = fmaf(v0, f.x, acc[0]); acc[1] = fmaf(v0, f.y, acc[1]);
        f = h2f(u0.y); acc[2] = fmaf(v0, f.x, acc[2]); acc[3] = fmaf(v0, f.y, acc[3]);
        f = h2f(u0.z); acc[4] = fmaf(v0, f.x, acc[4]); acc[5] = fmaf(v0, f.y, acc[5]);
        f = h2f(u0.w); acc[6] = fmaf(v0, f.x, acc[6]); acc[7] = fmaf(v0, f.y, acc[7]);
        f = h2f(u1.x); acc[0] = fmaf(v1, f.x, acc[0]); acc[1] = fmaf(v1, f.y, acc[1]);
        f = h2f(u1.y); acc[2] = fmaf(v1, f.x, acc[2]); acc[3] = fmaf(v1, f.y, acc[3]);
        f = h2f(u1.z); acc[4] = fmaf(v1, f.x, acc[4]); acc[5] = fmaf(v1, f.y, acc[5]);
        f = h2f(u1.w); acc[6] = fmaf(v1, f.x, acc[6]); acc[7] = fmaf(v1, f.y, acc[7]);
        f = h2f(u2.x); acc[0] = fmaf(v2, f.x, acc[0]); acc[1] = fmaf(v2, f.y, acc[1]);
        f = h2f(u2.y); acc[2] = fmaf(v2, f.x, acc[2]); acc[3] = fmaf(v2, f.y, acc[3]);
        f = h2f(u2.z); acc[4] = fmaf(v2, f.x, acc[4]); acc[5] = fmaf(v2, f.y, acc[5]);
        f = h2f(u2.w); acc[6] = fmaf(v2, f.x, acc[6]); acc[7] = fmaf(v2, f.y, acc[7]);
        f = h2f(u3.x); acc[0] = fmaf(v3, f.x, acc[0]); acc[1] = fmaf(v3, f.y, acc[1]);
        f = h2f(u3.y); acc[2] = fmaf(v3, f.x, acc[2]); acc[3] = fmaf(v3, f.y, acc[3]);
        f = h2f(u3.z); acc[4] = fmaf(v3, f.x, acc[4]); acc[5] = fmaf(v3, f.y, acc[5]);
        f = h2f(u3.w); acc[6] = fmaf(v3, f.x, acc[6]); acc[7] = fmaf(v3, f.y, acc[7]);
    }

    // tile[lj][8sub+i]: bank = (lj + 8sub + i) mod 32 -> 2 lanes/bank = free
    #pragma unroll
    for (int i = 0; i < 8; ++i) tile[lj][(sub << 3) + i] = acc[i];
    __syncthreads();

    const int rc = r0 + lane;
    if (rc < OUT_F) {
        const float bv = bias[rc];
        for (int bb = w; bb < 64; bb += 8)
            out[(size_t)bb * OUT_F + rc] = tile[lane][bb] + bv;
    }
}

// ---------------------------------------------------------------------------
// Fallback (insufficient ws): gather from native x layout. Correct, slow.
// ---------------------------------------------------------------------------
__global__ __launch_bounds__(256) void k_spmm_fallback(
    const float* __restrict__ x,
    const float* __restrict__ vals,
    const int*   __restrict__ rows,
    const int*   __restrict__ cols,
    const float* __restrict__ bias,
    float* __restrict__ out) {
    __shared__ int   rstart[65];
    __shared__ float tile[64][65];
    const int r0   = blockIdx.x * 64;
    const int t    = threadIdx.x;
    const int lane = t & 63;
    const int w    = t >> 6;
    if (t < 65) {
        const int target = r0 + t;
        int lo = 0, hi = NNZ_N;
        while (lo < hi) {
            const int mid = (lo + hi) >> 1;
            if (rows[mid] < target) lo = mid + 1; else hi = mid;
        }
        rstart[t] = lo;
    }
    __syncthreads();
    for (int j = w; j < 64; j += 4) {
        const int s = rstart[j], e = rstart[j + 1];
        float acc = 0.f;
        const size_t base = (size_t)lane * IN_F;
        for (int idx = s; idx < e; ++idx)
            acc = fmaf(vals[idx], x[base + cols[idx]], acc);
        tile[j][lane] = acc;
    }
    __syncthreads();
    const int c = lane;
    if (r0 + c < OUT_F) {
        const float bv = bias[r0 + c];
        for (int bb = w; bb < 64; bb += 4)
            out[(size_t)bb * OUT_F + (r0 + c)] = tile[c][bb] + bv;
    }
}

extern "C" void kernel_launch(void* const* d_in, const int* in_sizes, int n_in,
                              void* d_out, int out_size, void* d_ws, size_t ws_size,
                              hipStream_t stream) {
    const float* x      = (const float*)d_in[0];
    const float* values = (const float*)d_in[1];
    const float* bias   = (const float*)d_in[2];
    const int*   rows   = (const int*)d_in[3];
    const int*   cols   = (const int*)d_in[4];
    float*       out    = (float*)d_out;

    const size_t xh_bytes = (size_t)IN_F * 32 * sizeof(unsigned);   // 12.8 MB
    const size_t rs_off   = (xh_bytes + 255) & ~(size_t)255;
    const size_t rs_bytes = (size_t)(OUT_F + 1) * sizeof(int);
    const size_t pr_off   = (rs_off + rs_bytes + 255) & ~(size_t)255;
    const size_t need     = pr_off + (size_t)NNZ_N * sizeof(uint2); // ~26 MB

    const int row_blocks = (OUT_F + 63) / 64;   // 1563

    if (ws_size >= need) {
        unsigned* xh     = (unsigned*)d_ws;
        int*      rstart = (int*)((char*)d_ws + rs_off);
        uint2*    pairs  = (uint2*)((char*)d_ws + pr_off);
        k_prep<<<TBLK + SBLK, 256, 0, stream>>>(x, rows, cols, values, xh, rstart, pairs);
        k_spmm<<<row_blocks, 512, 0, stream>>>(
            (const uint4*)xh, pairs, rstart, bias, out);
    } else {
        k_spmm_fallback<<<row_blocks, 256, 0, stream>>>(x, values, rows, cols, bias, out);
    }
}